// Round 1
// baseline (591.640 us; speedup 1.0000x reference)
//
#include <hip/hip_runtime.h>
#include <cstdint>

// Problem constants (from setup_inputs: B=8, C=80, H=W=128, K=100, kernel=3, num_dets=1000)
#define NB    8
#define NC    80
#define HH    128
#define WW    128
#define HW    16384       // 128*128
#define CHW   1310720     // 80*16384
#define KTOP  100
#define NDET  1000
#define NPAIR 10000
#define CAP   4096        // candidate cap per (tensor,batch)
#define ACAP  2048        // accepted-pair cap per batch
#define NBINS 4096        // histogram bins over float bits >> 19

// ---- workspace layout (bytes) ----
#define OFF_CAND   0                            // uint64 [24][CAP]
#define OFF_ACC    (OFF_CAND + 24*CAP*8)        // uint64 [8][ACAP]
#define OFF_HIST   (OFF_ACC  + 8*ACAP*8)        // uint32 [24][NBINS]
#define OFF_CCNT   (OFF_HIST + 24*NBINS*4)      // int [24]
#define OFF_ACNT   (OFF_CCNT + 24*4)            // int [8]
#define OFF_THR    (OFF_ACNT + 8*4)             // int [24]
#define OFF_CS     (OFF_THR  + 24*4)            // float [24*100]  scores
#define OFF_CX     (OFF_CS   + 2400*4)          // float [24*100]  x + off0
#define OFF_CY     (OFF_CX   + 2400*4)          // float [24*100]  y + off1
#define OFF_CE     (OFF_CY   + 2400*4)          // float [24*100]  embedding
#define OFF_CCLS   (OFF_CE   + 2400*4)          // int   [24*100]  class
#define WS_NEEDED  (OFF_CCLS + 2400*4)
#define ZERO_OFF   OFF_HIST
#define ZERO_BYTES (OFF_CS - OFF_HIST)

// jax.nn.sigmoid-compatible branch structure (minimize ulp drift vs reference)
__device__ __forceinline__ float sigmoidf(float x) {
    if (x >= 0.f) return 1.f / (1.f + expf(-x));
    float e = expf(x);
    return e / (1.f + e);
}

// local-max test on RAW heat (sigmoid is monotone -> same mask, exact)
__device__ __forceinline__ bool is_local_max(const float* __restrict__ hb, int idx, float v) {
    int rem = idx & (HW - 1);
    int y = rem >> 7, x = rem & (WW - 1);
    bool xm = (x > 0), xp = (x < WW - 1);
    bool mx = true;
    if (y > 0) {
        const float* r = hb + idx - WW;
        if (xm && r[-1] > v) mx = false;
        if (r[0] > v)        mx = false;
        if (xp && r[1] > v)  mx = false;
    }
    {
        const float* r = hb + idx;
        if (xm && r[-1] > v) mx = false;
        if (xp && r[1] > v)  mx = false;
    }
    if (y < HH - 1) {
        const float* r = hb + idx + WW;
        if (xm && r[-1] > v) mx = false;
        if (r[0] > v)        mx = false;
        if (xp && r[1] > v)  mx = false;
    }
    return mx;
}

// ---- kernel 1: NMS + histogram of surviving sigmoid values ----
__global__ void k_nms_hist(const float* __restrict__ tl, const float* __restrict__ br,
                           const float* __restrict__ ct, uint32_t* __restrict__ hist) {
    __shared__ uint32_t lh[NBINS];
    for (int i = threadIdx.x; i < NBINS; i += 256) lh[i] = 0;
    __syncthreads();
    int bc = blockIdx.y; int t = bc >> 3; int b = bc & 7;
    const float* heat = (t == 0) ? tl : (t == 1) ? br : ct;
    const float* hb = heat + (size_t)b * CHW;
    int base = blockIdx.x * 2048;
    for (int it = 0; it < 8; ++it) {
        int idx = base + it * 256 + threadIdx.x;
        float v = hb[idx];
        if (is_local_max(hb, idx, v)) {
            float s = sigmoidf(v);
            uint32_t bin = __float_as_uint(s) >> 19;   // positive floats: bits order == value order
            atomicAdd(&lh[bin], 1u);
        }
    }
    __syncthreads();
    uint32_t* gh = hist + (size_t)bc * NBINS;
    for (int i = threadIdx.x; i < NBINS; i += 256) {
        uint32_t c = lh[i];
        if (c) atomicAdd(&gh[i], c);
    }
}

// ---- kernel 2: find threshold bin so that count(bins >= T) >= KTOP ----
__global__ void k_thresh(const uint32_t* __restrict__ hist, int* __restrict__ thr) {
    int bc = threadIdx.x;
    if (bc >= 24) return;
    const uint32_t* h = hist + (size_t)bc * NBINS;
    uint32_t cum = 0; int T = 1;
    for (int bin = NBINS - 1; bin >= 1; --bin) {
        cum += h[bin];
        if (cum >= KTOP) { T = bin; break; }
    }
    thr[bc] = T;
}

// ---- kernel 3: recompute NMS, compact candidates with bin >= T ----
__global__ void k_collect(const float* __restrict__ tl, const float* __restrict__ br,
                          const float* __restrict__ ct, const int* __restrict__ thr,
                          uint64_t* __restrict__ cand, int* __restrict__ ccnt) {
    int bc = blockIdx.y; int t = bc >> 3; int b = bc & 7;
    const float* heat = (t == 0) ? tl : (t == 1) ? br : ct;
    const float* hb = heat + (size_t)b * CHW;
    int T = thr[bc];
    int base = blockIdx.x * 2048;
    for (int it = 0; it < 8; ++it) {
        int idx = base + it * 256 + threadIdx.x;
        float v = hb[idx];
        if (is_local_max(hb, idx, v)) {
            float s = sigmoidf(v);
            uint32_t bits = __float_as_uint(s);
            if ((int)(bits >> 19) >= T) {
                int pos = atomicAdd(&ccnt[bc], 1);
                if (pos < CAP)
                    cand[(size_t)bc * CAP + pos] =
                        ((uint64_t)bits << 32) | (uint32_t)(~(uint32_t)idx); // tie: smaller idx wins
            }
        }
    }
}

// descending bitonic sort of N u64 keys in LDS
template <int N>
__device__ void bitonic_desc(uint64_t* k) {
    for (int kk = 2; kk <= N; kk <<= 1) {
        for (int j = kk >> 1; j > 0; j >>= 1) {
            __syncthreads();
            for (int i = threadIdx.x; i < N; i += blockDim.x) {
                int l = i ^ j;
                if (l > i) {
                    uint64_t a = k[i], b = k[l];
                    bool up = ((i & kk) == 0);
                    if (up ? (a < b) : (a > b)) { k[i] = b; k[l] = a; }
                }
            }
        }
    }
    __syncthreads();
}

// ---- kernel 4: per (tensor,batch) sort candidates, emit top-100 corner data ----
__global__ void __launch_bounds__(1024) k_select(
        const uint64_t* __restrict__ cand, const int* __restrict__ ccnt,
        const float* __restrict__ tl_tag, const float* __restrict__ br_tag,
        const float* __restrict__ tl_regr, const float* __restrict__ br_regr,
        const float* __restrict__ ct_regr,
        float* __restrict__ cs, float* __restrict__ cx, float* __restrict__ cy,
        float* __restrict__ ce, int* __restrict__ ccls) {
    __shared__ uint64_t keys[CAP];
    int bc = blockIdx.x; int t = bc >> 3; int b = bc & 7;
    int n = ccnt[bc]; if (n > CAP) n = CAP;
    for (int i = threadIdx.x; i < CAP; i += 1024)
        keys[i] = (i < n) ? cand[(size_t)bc * CAP + i] : 0ull;
    bitonic_desc<CAP>(keys);
    if (threadIdx.x < KTOP) {
        uint64_t key = keys[threadIdx.x];
        float s = __uint_as_float((uint32_t)(key >> 32));
        uint32_t idx = ~(uint32_t)key;
        int cls = (int)(idx >> 14);          // / HW
        int rem = (int)(idx & (HW - 1));
        int y = rem >> 7, x = rem & (WW - 1);
        const float* regr = (t == 0) ? tl_regr : (t == 1) ? br_regr : ct_regr;
        float o0 = regr[((size_t)b * 2 + 0) * HW + rem];
        float o1 = regr[((size_t)b * 2 + 1) * HW + rem];
        float emb = 0.f;
        if (t == 0) emb = tl_tag[(size_t)b * HW + rem];
        else if (t == 1) emb = br_tag[(size_t)b * HW + rem];
        int o = bc * KTOP + threadIdx.x;
        cs[o] = s;
        cx[o] = (float)x + o0;
        cy[o] = (float)y + o1;
        ce[o] = emb;
        ccls[o] = cls;
    }
}

// ---- kernel 5: pairwise scoring, compact accepted pairs ----
__global__ void __launch_bounds__(1024) k_pairs(
        const float* __restrict__ cs, const float* __restrict__ cx,
        const float* __restrict__ cy, const float* __restrict__ ce,
        const int* __restrict__ ccls,
        uint64_t* __restrict__ acc, int* __restrict__ acnt) {
    int b = blockIdx.x;
    __shared__ float ts[KTOP], tx[KTOP], ty[KTOP], te[KTOP];
    __shared__ int   tc[KTOP];
    __shared__ float bs_[KTOP], bx[KTOP], by[KTOP], be[KTOP];
    __shared__ int   bcl[KTOP];
    int tid = threadIdx.x;
    if (tid < KTOP) {
        int o = (0 * NB + b) * KTOP + tid;
        ts[tid] = cs[o]; tx[tid] = cx[o]; ty[tid] = cy[o]; te[tid] = ce[o]; tc[tid] = ccls[o];
    } else if (tid >= 512 && tid < 512 + KTOP) {
        int k = tid - 512;
        int o = (1 * NB + b) * KTOP + k;
        bs_[k] = cs[o]; bx[k] = cx[o]; by[k] = cy[o]; be[k] = ce[o]; bcl[k] = ccls[o];
    }
    __syncthreads();
    for (int p = tid; p < NPAIR; p += 1024) {
        int i = p / KTOP, j = p - i * KTOP;
        bool rej = (tc[i] != bcl[j])
                 | (fabsf(te[i] - be[j]) > 0.5f)
                 | (bx[j] < tx[i])
                 | (by[j] < ty[i]);
        if (!rej) {
            float sc = (ts[i] + bs_[j]) * 0.5f;
            int pos = atomicAdd(&acnt[b], 1);
            if (pos < ACAP)
                acc[(size_t)b * ACAP + pos] =
                    ((uint64_t)__float_as_uint(sc) << 32) | (uint32_t)(~(uint32_t)p);
        }
    }
}

// ---- kernel 6: per-batch final top-1000 (accepted sorted desc, then -1 fills by asc index) ----
__global__ void __launch_bounds__(1024) k_final(
        const uint64_t* __restrict__ acc, const int* __restrict__ acnt,
        const float* __restrict__ cs, const float* __restrict__ cx,
        const float* __restrict__ cy, const int* __restrict__ ccls,
        float* __restrict__ out) {
    int b = blockIdx.x;
    __shared__ uint64_t keys[ACAP];
    __shared__ int aidx[ACAP];
    int m = acnt[b]; if (m > ACAP) m = ACAP;
    for (int i = threadIdx.x; i < ACAP; i += 1024)
        keys[i] = (i < m) ? acc[(size_t)b * ACAP + i] : 0ull;
    bitonic_desc<ACAP>(keys);
    if ((int)threadIdx.x < m) aidx[threadIdx.x] = (int)(~(uint32_t)keys[threadIdx.x]);
    __syncthreads();
    for (int d = threadIdx.x; d < NDET; d += 1024) {
        int p; float sc;
        if (d < m) {
            p = aidx[d];
            sc = __uint_as_float((uint32_t)(keys[d] >> 32));
        } else {
            // (d-m)-th index NOT in accepted set, ascending (stable top_k over ties at -1)
            int r = d - m;
            int idx = r;
            for (;;) {
                int c = 0;
                for (int a = 0; a < m; ++a) c += (aidx[a] <= idx) ? 1 : 0;
                int ni = r + c;
                if (ni == idx) break;
                idx = ni;
            }
            p = idx; sc = -1.f;
        }
        int i = p / KTOP, j = p - i * KTOP;
        int ot = (0 * NB + b) * KTOP + i;
        int ob = (1 * NB + b) * KTOP + j;
        float* dr = out + ((size_t)b * NDET + d) * 8;
        dr[0] = cx[ot]; dr[1] = cy[ot]; dr[2] = cx[ob]; dr[3] = cy[ob];
        dr[4] = sc; dr[5] = cs[ot]; dr[6] = cs[ob]; dr[7] = (float)ccls[ot];
    }
    if (threadIdx.x < KTOP) {
        int oc = (2 * NB + b) * KTOP + threadIdx.x;
        float* cr = out + (size_t)NB * NDET * 8 + ((size_t)b * KTOP + threadIdx.x) * 4;
        cr[0] = cx[oc]; cr[1] = cy[oc]; cr[2] = (float)ccls[oc]; cr[3] = cs[oc];
    }
}

extern "C" void kernel_launch(void* const* d_in, const int* in_sizes, int n_in,
                              void* d_out, int out_size, void* d_ws, size_t ws_size,
                              hipStream_t stream) {
    const float* tl_heat = (const float*)d_in[0];
    const float* br_heat = (const float*)d_in[1];
    const float* ct_heat = (const float*)d_in[2];
    const float* tl_tag  = (const float*)d_in[3];
    const float* br_tag  = (const float*)d_in[4];
    const float* tl_regr = (const float*)d_in[5];
    const float* br_regr = (const float*)d_in[6];
    const float* ct_regr = (const float*)d_in[7];
    // K=100, kernel=3, num_dets=1000 are compile-time constants above.

    if (ws_size < (size_t)WS_NEEDED) return;  // need ~1.36 MB scratch

    char* ws = (char*)d_ws;
    uint64_t* cand = (uint64_t*)(ws + OFF_CAND);
    uint64_t* acc  = (uint64_t*)(ws + OFF_ACC);
    uint32_t* hist = (uint32_t*)(ws + OFF_HIST);
    int*   ccnt = (int*)(ws + OFF_CCNT);
    int*   acnt = (int*)(ws + OFF_ACNT);
    int*   thr  = (int*)(ws + OFF_THR);
    float* cs   = (float*)(ws + OFF_CS);
    float* cx   = (float*)(ws + OFF_CX);
    float* cy   = (float*)(ws + OFF_CY);
    float* ce   = (float*)(ws + OFF_CE);
    int*   ccls = (int*)(ws + OFF_CCLS);

    // zero hist + counters (ws is poisoned 0xAA and NOT re-poisoned between replays)
    hipMemsetAsync(ws + ZERO_OFF, 0, ZERO_BYTES, stream);

    dim3 gscan(CHW / 2048, 24);
    k_nms_hist<<<gscan, 256, 0, stream>>>(tl_heat, br_heat, ct_heat, hist);
    k_thresh<<<1, 64, 0, stream>>>(hist, thr);
    k_collect<<<gscan, 256, 0, stream>>>(tl_heat, br_heat, ct_heat, thr, cand, ccnt);
    k_select<<<24, 1024, 0, stream>>>(cand, ccnt, tl_tag, br_tag,
                                      tl_regr, br_regr, ct_regr,
                                      cs, cx, cy, ce, ccls);
    k_pairs<<<NB, 1024, 0, stream>>>(cs, cx, cy, ce, ccls, acc, acnt);
    k_final<<<NB, 1024, 0, stream>>>(acc, acnt, cs, cx, cy, ccls, (float*)d_out);
}

// Round 2
// 264.075 us; speedup vs baseline: 2.2404x; 2.2404x over previous
//
#include <hip/hip_runtime.h>
#include <cstdint>

// Problem constants (B=8, C=80, H=W=128, K=100, kernel=3, num_dets=1000)
#define NB    8
#define NC    80
#define HH    128
#define WW    128
#define HW    16384
#define CHW   1310720
#define KTOP  100
#define NDET  1000
#define NPAIR 10000
#define CAP   4096
#define ACAP  2048
#define NBINS 4096

// ---- workspace layout (bytes) ----
#define OFF_CAND   0                            // uint64 [24][CAP]
#define OFF_ACC    (OFF_CAND + 24*CAP*8)        // uint64 [8][ACAP]
#define OFF_HIST   (OFF_ACC  + 8*ACAP*8)        // uint32 [24][NBINS]
#define OFF_CCNT   (OFF_HIST + 24*NBINS*4)      // int [24]
#define OFF_ACNT   (OFF_CCNT + 24*4)            // int [8]
#define OFF_THR    (OFF_ACNT + 8*4)             // int [24]
#define OFF_CS     (OFF_THR  + 24*4)            // float [24*100]
#define OFF_CX     (OFF_CS   + 2400*4)
#define OFF_CY     (OFF_CX   + 2400*4)
#define OFF_CE     (OFF_CY   + 2400*4)
#define OFF_CCLS   (OFF_CE   + 2400*4)
#define WS_NEEDED  (OFF_CCLS + 2400*4)
#define ZERO_OFF   OFF_HIST
#define ZERO_BYTES (OFF_CS - OFF_HIST)

__device__ __forceinline__ float sigmoidf(float x) {
    if (x >= 0.f) return 1.f / (1.f + expf(-x));
    float e = expf(x);
    return e / (1.f + e);
}

// vectorized 4-pixel NMS on raw heat (sigmoid monotone -> identical mask)
// returns 4-bit survivor mask; loads mid row into m
__device__ __forceinline__ uint32_t nms4(const float* __restrict__ hb, int idx4, float4& m) {
    const float NEG = -__builtin_inff();
    int rem = idx4 & (HW - 1);
    int y = rem >> 7, x = rem & (WW - 1);
    bool xm = (x > 0), xp = (x < WW - 4);
    m = *(const float4*)(hb + idx4);
    float ml = xm ? hb[idx4 - 1] : NEG;
    float mr = xp ? hb[idx4 + 4] : NEG;
    float4 u; float ul, ur;
    if (y > 0) {
        u = *(const float4*)(hb + idx4 - WW);
        ul = xm ? hb[idx4 - WW - 1] : NEG;
        ur = xp ? hb[idx4 - WW + 4] : NEG;
    } else { u = make_float4(NEG, NEG, NEG, NEG); ul = NEG; ur = NEG; }
    float4 d; float dl, dr;
    if (y < HH - 1) {
        d = *(const float4*)(hb + idx4 + WW);
        dl = xm ? hb[idx4 + WW - 1] : NEG;
        dr = xp ? hb[idx4 + WW + 4] : NEG;
    } else { d = make_float4(NEG, NEG, NEG, NEG); dl = NEG; dr = NEG; }

    float mv[6] = {ml, m.x, m.y, m.z, m.w, mr};
    float uv[6] = {ul, u.x, u.y, u.z, u.w, ur};
    float dv[6] = {dl, d.x, d.y, d.z, d.w, dr};
    uint32_t mask = 0;
    #pragma unroll
    for (int p = 0; p < 4; ++p) {
        float v = mv[p + 1];
        bool mx = !(uv[p] > v || uv[p+1] > v || uv[p+2] > v ||
                    mv[p] > v ||                mv[p+2] > v ||
                    dv[p] > v || dv[p+1] > v || dv[p+2] > v);
        mask |= (mx ? 1u : 0u) << p;
    }
    return mask;
}

// ---- kernel 1: NMS + histogram of surviving sigmoid values ----
__global__ void __launch_bounds__(256) k_nms_hist(
        const float* __restrict__ tl, const float* __restrict__ br,
        const float* __restrict__ ct, uint32_t* __restrict__ hist) {
    __shared__ uint32_t lh[NBINS];
    for (int i = threadIdx.x; i < NBINS; i += 256) lh[i] = 0;
    __syncthreads();
    int bc = blockIdx.y; int t = bc >> 3; int b = bc & 7;
    const float* heat = (t == 0) ? tl : (t == 1) ? br : ct;
    const float* hb = heat + (size_t)b * CHW;
    int base = blockIdx.x * 8192;
    #pragma unroll
    for (int it = 0; it < 8; ++it) {
        int idx4 = base + it * 1024 + threadIdx.x * 4;
        float4 m;
        uint32_t mask = nms4(hb, idx4, m);
        if (mask) {
            float mv[4] = {m.x, m.y, m.z, m.w};
            #pragma unroll
            for (int p = 0; p < 4; ++p)
                if (mask & (1u << p)) {
                    uint32_t bin = __float_as_uint(sigmoidf(mv[p])) >> 19;
                    atomicAdd(&lh[bin], 1u);
                }
        }
    }
    __syncthreads();
    uint32_t* gh = hist + (size_t)bc * NBINS;
    for (int i = threadIdx.x; i < NBINS; i += 256) {
        uint32_t c = lh[i];
        if (c) atomicAdd(&gh[i], c);
    }
}

// ---- kernel 2: parallel threshold find (one block per bc) ----
// T = largest bin>=1 with suffix_count(T) >= K, else 1 (identical to serial ref)
__global__ void __launch_bounds__(256) k_thresh(const uint32_t* __restrict__ hist,
                                                int* __restrict__ thr) {
    __shared__ uint32_t csum[256];
    int bc = blockIdx.x;
    const uint32_t* h = hist + (size_t)bc * NBINS;
    int tid = threadIdx.x;
    uint32_t bins[16];
    #pragma unroll
    for (int i = 0; i < 16; ++i) bins[i] = h[tid * 16 + i];
    if (tid == 0) bins[0] = 0;  // bin 0 excluded from threshold search
    uint32_t s = 0;
    #pragma unroll
    for (int i = 0; i < 16; ++i) s += bins[i];
    csum[tid] = s;
    __syncthreads();
    for (int step = 1; step < 256; step <<= 1) {
        uint32_t add = (tid + step < 256) ? csum[tid + step] : 0;
        __syncthreads();
        csum[tid] += add;
        __syncthreads();
    }
    uint32_t inc = csum[tid];                       // S(chunk tid)
    uint32_t above = (tid + 1 < 256) ? csum[tid + 1] : 0;  // S(chunk tid+1)
    if (tid == 0 && inc < KTOP) thr[bc] = 1;        // total < K -> default
    if (above < KTOP && inc >= KTOP) {              // crossing inside this chunk
        uint32_t cum = above;
        int T = 1;
        #pragma unroll
        for (int i = 15; i >= 0; --i) {
            cum += bins[i];
            if (cum >= KTOP) { T = tid * 16 + i; break; }
        }
        thr[bc] = T;
    }
}

// ---- kernel 3: recompute NMS, compact candidates with bin >= T ----
__global__ void __launch_bounds__(256) k_collect(
        const float* __restrict__ tl, const float* __restrict__ br,
        const float* __restrict__ ct, const int* __restrict__ thr,
        uint64_t* __restrict__ cand, int* __restrict__ ccnt) {
    int bc = blockIdx.y; int t = bc >> 3; int b = bc & 7;
    const float* heat = (t == 0) ? tl : (t == 1) ? br : ct;
    const float* hb = heat + (size_t)b * CHW;
    int T = thr[bc];
    int base = blockIdx.x * 8192;
    #pragma unroll
    for (int it = 0; it < 8; ++it) {
        int idx4 = base + it * 1024 + threadIdx.x * 4;
        float4 m;
        uint32_t mask = nms4(hb, idx4, m);
        if (mask) {
            float mv[4] = {m.x, m.y, m.z, m.w};
            #pragma unroll
            for (int p = 0; p < 4; ++p)
                if (mask & (1u << p)) {
                    uint32_t bits = __float_as_uint(sigmoidf(mv[p]));
                    if ((int)(bits >> 19) >= T) {
                        int pos = atomicAdd(&ccnt[bc], 1);
                        if (pos < CAP)
                            cand[(size_t)bc * CAP + pos] =
                                ((uint64_t)bits << 32) | (uint32_t)(~(uint32_t)(idx4 + p));
                    }
                }
        }
    }
}

// descending bitonic sort of N u64 keys in LDS
template <int N>
__device__ void bitonic_desc(uint64_t* k) {
    for (int kk = 2; kk <= N; kk <<= 1) {
        for (int j = kk >> 1; j > 0; j >>= 1) {
            __syncthreads();
            for (int i = threadIdx.x; i < N; i += blockDim.x) {
                int l = i ^ j;
                if (l > i) {
                    uint64_t a = k[i], b = k[l];
                    bool up = ((i & kk) == 0);
                    if (up ? (a < b) : (a > b)) { k[i] = b; k[l] = a; }
                }
            }
        }
    }
    __syncthreads();
}

// ---- kernel 4: per (tensor,batch) sort candidates, emit top-100 corner data ----
__global__ void __launch_bounds__(1024) k_select(
        const uint64_t* __restrict__ cand, const int* __restrict__ ccnt,
        const float* __restrict__ tl_tag, const float* __restrict__ br_tag,
        const float* __restrict__ tl_regr, const float* __restrict__ br_regr,
        const float* __restrict__ ct_regr,
        float* __restrict__ cs, float* __restrict__ cx, float* __restrict__ cy,
        float* __restrict__ ce, int* __restrict__ ccls) {
    __shared__ uint64_t keys[CAP];
    int bc = blockIdx.x; int t = bc >> 3; int b = bc & 7;
    int n = ccnt[bc]; if (n > CAP) n = CAP;
    for (int i = threadIdx.x; i < CAP; i += 1024)
        keys[i] = (i < n) ? cand[(size_t)bc * CAP + i] : 0ull;
    bitonic_desc<CAP>(keys);
    if (threadIdx.x < KTOP) {
        uint64_t key = keys[threadIdx.x];
        float s = __uint_as_float((uint32_t)(key >> 32));
        uint32_t idx = ~(uint32_t)key;
        int cls = (int)(idx >> 14);
        int rem = (int)(idx & (HW - 1));
        int y = rem >> 7, x = rem & (WW - 1);
        const float* regr = (t == 0) ? tl_regr : (t == 1) ? br_regr : ct_regr;
        float o0 = regr[((size_t)b * 2 + 0) * HW + rem];
        float o1 = regr[((size_t)b * 2 + 1) * HW + rem];
        float emb = 0.f;
        if (t == 0) emb = tl_tag[(size_t)b * HW + rem];
        else if (t == 1) emb = br_tag[(size_t)b * HW + rem];
        int o = bc * KTOP + threadIdx.x;
        cs[o] = s;
        cx[o] = (float)x + o0;
        cy[o] = (float)y + o1;
        ce[o] = emb;
        ccls[o] = cls;
    }
}

// ---- kernel 5: pairwise scoring, compact accepted pairs ----
__global__ void __launch_bounds__(1024) k_pairs(
        const float* __restrict__ cs, const float* __restrict__ cx,
        const float* __restrict__ cy, const float* __restrict__ ce,
        const int* __restrict__ ccls,
        uint64_t* __restrict__ acc, int* __restrict__ acnt) {
    int b = blockIdx.x;
    __shared__ float ts[KTOP], tx[KTOP], ty[KTOP], te[KTOP];
    __shared__ int   tc[KTOP];
    __shared__ float bs_[KTOP], bx[KTOP], by[KTOP], be[KTOP];
    __shared__ int   bcl[KTOP];
    int tid = threadIdx.x;
    if (tid < KTOP) {
        int o = (0 * NB + b) * KTOP + tid;
        ts[tid] = cs[o]; tx[tid] = cx[o]; ty[tid] = cy[o]; te[tid] = ce[o]; tc[tid] = ccls[o];
    } else if (tid >= 512 && tid < 512 + KTOP) {
        int k = tid - 512;
        int o = (1 * NB + b) * KTOP + k;
        bs_[k] = cs[o]; bx[k] = cx[o]; by[k] = cy[o]; be[k] = ce[o]; bcl[k] = ccls[o];
    }
    __syncthreads();
    for (int p = tid; p < NPAIR; p += 1024) {
        int i = p / KTOP, j = p - i * KTOP;
        bool rej = (tc[i] != bcl[j])
                 | (fabsf(te[i] - be[j]) > 0.5f)
                 | (bx[j] < tx[i])
                 | (by[j] < ty[i]);
        if (!rej) {
            float sc = (ts[i] + bs_[j]) * 0.5f;
            int pos = atomicAdd(&acnt[b], 1);
            if (pos < ACAP)
                acc[(size_t)b * ACAP + pos] =
                    ((uint64_t)__float_as_uint(sc) << 32) | (uint32_t)(~(uint32_t)p);
        }
    }
}

// ---- kernel 6: per-batch final top-1000 ----
__global__ void __launch_bounds__(1024) k_final(
        const uint64_t* __restrict__ acc, const int* __restrict__ acnt,
        const float* __restrict__ cs, const float* __restrict__ cx,
        const float* __restrict__ cy, const int* __restrict__ ccls,
        float* __restrict__ out) {
    int b = blockIdx.x;
    __shared__ uint64_t keys[ACAP];
    __shared__ int aidx[ACAP];
    int m = acnt[b]; if (m > ACAP) m = ACAP;
    for (int i = threadIdx.x; i < ACAP; i += 1024)
        keys[i] = (i < m) ? acc[(size_t)b * ACAP + i] : 0ull;
    bitonic_desc<ACAP>(keys);
    if ((int)threadIdx.x < m) aidx[threadIdx.x] = (int)(~(uint32_t)keys[threadIdx.x]);
    __syncthreads();
    for (int d = threadIdx.x; d < NDET; d += 1024) {
        int p; float sc;
        if (d < m) {
            p = aidx[d];
            sc = __uint_as_float((uint32_t)(keys[d] >> 32));
        } else {
            int r = d - m;
            int idx = r;
            for (;;) {
                int c = 0;
                for (int a = 0; a < m; ++a) c += (aidx[a] <= idx) ? 1 : 0;
                int ni = r + c;
                if (ni == idx) break;
                idx = ni;
            }
            p = idx; sc = -1.f;
        }
        int i = p / KTOP, j = p - i * KTOP;
        int ot = (0 * NB + b) * KTOP + i;
        int ob = (1 * NB + b) * KTOP + j;
        float* dr = out + ((size_t)b * NDET + d) * 8;
        dr[0] = cx[ot]; dr[1] = cy[ot]; dr[2] = cx[ob]; dr[3] = cy[ob];
        dr[4] = sc; dr[5] = cs[ot]; dr[6] = cs[ob]; dr[7] = (float)ccls[ot];
    }
    if (threadIdx.x < KTOP) {
        int oc = (2 * NB + b) * KTOP + threadIdx.x;
        float* cr = out + (size_t)NB * NDET * 8 + ((size_t)b * KTOP + threadIdx.x) * 4;
        cr[0] = cx[oc]; cr[1] = cy[oc]; cr[2] = (float)ccls[oc]; cr[3] = cs[oc];
    }
}

extern "C" void kernel_launch(void* const* d_in, const int* in_sizes, int n_in,
                              void* d_out, int out_size, void* d_ws, size_t ws_size,
                              hipStream_t stream) {
    const float* tl_heat = (const float*)d_in[0];
    const float* br_heat = (const float*)d_in[1];
    const float* ct_heat = (const float*)d_in[2];
    const float* tl_tag  = (const float*)d_in[3];
    const float* br_tag  = (const float*)d_in[4];
    const float* tl_regr = (const float*)d_in[5];
    const float* br_regr = (const float*)d_in[6];
    const float* ct_regr = (const float*)d_in[7];

    if (ws_size < (size_t)WS_NEEDED) return;

    char* ws = (char*)d_ws;
    uint64_t* cand = (uint64_t*)(ws + OFF_CAND);
    uint64_t* acc  = (uint64_t*)(ws + OFF_ACC);
    uint32_t* hist = (uint32_t*)(ws + OFF_HIST);
    int*   ccnt = (int*)(ws + OFF_CCNT);
    int*   acnt = (int*)(ws + OFF_ACNT);
    int*   thr  = (int*)(ws + OFF_THR);
    float* cs   = (float*)(ws + OFF_CS);
    float* cx   = (float*)(ws + OFF_CX);
    float* cy   = (float*)(ws + OFF_CY);
    float* ce   = (float*)(ws + OFF_CE);
    int*   ccls = (int*)(ws + OFF_CCLS);

    hipMemsetAsync(ws + ZERO_OFF, 0, ZERO_BYTES, stream);

    dim3 gscan(CHW / 8192, 24);   // (160, 24)
    k_nms_hist<<<gscan, 256, 0, stream>>>(tl_heat, br_heat, ct_heat, hist);
    k_thresh<<<24, 256, 0, stream>>>(hist, thr);
    k_collect<<<gscan, 256, 0, stream>>>(tl_heat, br_heat, ct_heat, thr, cand, ccnt);
    k_select<<<24, 1024, 0, stream>>>(cand, ccnt, tl_tag, br_tag,
                                      tl_regr, br_regr, ct_regr,
                                      cs, cx, cy, ce, ccls);
    k_pairs<<<NB, 1024, 0, stream>>>(cs, cx, cy, ce, ccls, acc, acnt);
    k_final<<<NB, 1024, 0, stream>>>(acc, acnt, cs, cx, cy, ccls, (float*)d_out);
}

// Round 3
// 179.368 us; speedup vs baseline: 3.2985x; 1.4723x over previous
//
#include <hip/hip_runtime.h>
#include <cstdint>

// Problem constants (B=8, C=80, H=W=128, K=100, kernel=3, num_dets=1000)
#define NB    8
#define NC    80
#define HH    128
#define WW    128
#define HW    16384
#define CHW   1310720
#define KTOP  100
#define NDET  1000
#define NPAIR 10000
#define CAP   4096
#define ACAP  2048
#define NBINS 4096
#define SBLK  2048        // per-block LDS survivor staging (expected ~910)
#define SCAP_MAX 262144   // per-bc survivor list cap (expected ~145K)

// ---- workspace layout (bytes) ----
#define OFF_CAND   0                            // uint64 [24][CAP]
#define OFF_ACC    (OFF_CAND + 24*CAP*8)        // uint64 [8][ACAP]
#define OFF_HIST   (OFF_ACC  + 8*ACAP*8)        // uint32 [24][NBINS]
#define OFF_CCNT   (OFF_HIST + 24*NBINS*4)      // int [24]
#define OFF_ACNT   (OFF_CCNT + 24*4)            // int [8]
#define OFF_SCNT   (OFF_ACNT + 8*4)             // int [24]
#define OFF_OVF    (OFF_SCNT + 24*4)            // int [24]
#define OFF_THR    (OFF_OVF  + 24*4)            // int [24]
#define OFF_CS     (OFF_THR  + 24*4)            // float [24*100]
#define OFF_CX     (OFF_CS   + 2400*4)
#define OFF_CY     (OFF_CX   + 2400*4)
#define OFF_CE     (OFF_CY   + 2400*4)
#define OFF_CCLS   (OFF_CE   + 2400*4)
#define OFF_SURV   (OFF_CCLS + 2400*4)          // uint64 [24][scap]
#define ZERO_OFF   OFF_HIST
#define ZERO_BYTES (OFF_CS - OFF_HIST)

__device__ __forceinline__ float sigmoidf(float x) {
    if (x >= 0.f) return 1.f / (1.f + expf(-x));
    float e = expf(x);
    return e / (1.f + e);
}

// ---- kernel 1: fused NMS + histogram + survivor staging ----
// survivor iff 3x3 window max == center (exactly the reference's reduce_window test;
// sigmoid monotone -> identical mask on raw heat)
__global__ void __launch_bounds__(256) k_nms_hist(
        const float* __restrict__ tl, const float* __restrict__ br,
        const float* __restrict__ ct, uint32_t* __restrict__ hist,
        uint64_t* __restrict__ surv, int* __restrict__ scnt,
        int* __restrict__ ovf, int scap) {
    __shared__ uint32_t lh2[NBINS / 2];   // two u16 bins per u32 (block cnt < 65536)
    __shared__ uint64_t lsurv[SBLK];
    __shared__ int lcnt, lbase;
    for (int i = threadIdx.x; i < NBINS / 2; i += 256) lh2[i] = 0;
    if (threadIdx.x == 0) lcnt = 0;
    __syncthreads();

    int bc = blockIdx.y; int t = bc >> 3; int b = bc & 7;
    const float* heat = (t == 0) ? tl : (t == 1) ? br : ct;
    const float* hb = heat + (size_t)b * CHW;
    int base = blockIdx.x * 8192;
    const float NEG = -__builtin_inff();

    #pragma unroll
    for (int it = 0; it < 8; ++it) {
        int idx4 = base + it * 1024 + threadIdx.x * 4;
        int rem = idx4 & (HW - 1);
        int y = rem >> 7, x = rem & (WW - 1);
        float4 m4 = *(const float4*)(hb + idx4);
        float4 u4 = make_float4(NEG, NEG, NEG, NEG);
        float4 d4 = make_float4(NEG, NEG, NEG, NEG);
        if (y > 0)      u4 = *(const float4*)(hb + idx4 - WW);
        if (y < HH - 1) d4 = *(const float4*)(hb + idx4 + WW);
        // column maxes (v_max3), then boundary columns from adjacent lanes:
        // 32 lanes cover one row of 128, so wave edges are exactly row edges.
        float c0 = fmaxf(fmaxf(u4.x, m4.x), d4.x);
        float c1 = fmaxf(fmaxf(u4.y, m4.y), d4.y);
        float c2 = fmaxf(fmaxf(u4.z, m4.z), d4.z);
        float c3 = fmaxf(fmaxf(u4.w, m4.w), d4.w);
        float cl = __shfl_up(c3, 1u);
        float cr = __shfl_down(c0, 1u);
        if (x == 0)      cl = NEG;
        if (x == WW - 4) cr = NEG;
        float w0 = fmaxf(fmaxf(cl, c0), c1);
        float w1 = fmaxf(fmaxf(c0, c1), c2);
        float w2 = fmaxf(fmaxf(c1, c2), c3);
        float w3 = fmaxf(fmaxf(c2, c3), cr);
        #define EMIT(W, V, P) \
            if ((W) == (V)) { \
                uint32_t bt = __float_as_uint(sigmoidf(V)); \
                uint32_t bin = bt >> 19; \
                atomicAdd(&lh2[bin >> 1], 1u << ((bin & 1) * 16)); \
                int p_ = atomicAdd(&lcnt, 1); \
                if (p_ < SBLK) \
                    lsurv[p_] = ((uint64_t)bt << 32) | (uint32_t)(~(uint32_t)(idx4 + (P))); \
            }
        EMIT(w0, m4.x, 0)
        EMIT(w1, m4.y, 1)
        EMIT(w2, m4.z, 2)
        EMIT(w3, m4.w, 3)
        #undef EMIT
    }
    __syncthreads();
    // merge packed histogram
    uint32_t* gh = hist + (size_t)bc * NBINS;
    for (int i = threadIdx.x; i < NBINS / 2; i += 256) {
        uint32_t v = lh2[i];
        uint32_t lo = v & 0xFFFFu, hi = v >> 16;
        if (lo) atomicAdd(&gh[2 * i], lo);
        if (hi) atomicAdd(&gh[2 * i + 1], hi);
    }
    // flush survivors (coalesced)
    int cnt = lcnt;
    if (threadIdx.x == 0) {
        lbase = atomicAdd(&scnt[bc], cnt);
        if (cnt > SBLK) ovf[bc] = 1;
    }
    __syncthreads();
    int cc = min(cnt, SBLK);
    int gb = lbase;
    uint64_t* sv = surv + (size_t)bc * scap;
    for (int i = threadIdx.x; i < cc; i += 256)
        if (gb + i < scap) sv[gb + i] = lsurv[i];
}

// ---- kernel 2: parallel threshold find ----
__global__ void __launch_bounds__(256) k_thresh(const uint32_t* __restrict__ hist,
                                                int* __restrict__ thr) {
    __shared__ uint32_t csum[256];
    int bc = blockIdx.x;
    const uint32_t* h = hist + (size_t)bc * NBINS;
    int tid = threadIdx.x;
    uint32_t bins[16];
    #pragma unroll
    for (int i = 0; i < 16; ++i) bins[i] = h[tid * 16 + i];
    if (tid == 0) bins[0] = 0;  // bin 0 excluded
    uint32_t s = 0;
    #pragma unroll
    for (int i = 0; i < 16; ++i) s += bins[i];
    csum[tid] = s;
    __syncthreads();
    for (int step = 1; step < 256; step <<= 1) {
        uint32_t add = (tid + step < 256) ? csum[tid + step] : 0;
        __syncthreads();
        csum[tid] += add;
        __syncthreads();
    }
    uint32_t inc = csum[tid];
    uint32_t above = (tid + 1 < 256) ? csum[tid + 1] : 0;
    if (tid == 0 && inc < KTOP) thr[bc] = 1;
    if (above < KTOP && inc >= KTOP) {
        uint32_t cum = above;
        int T = 1;
        #pragma unroll
        for (int i = 15; i >= 0; --i) {
            cum += bins[i];
            if (cum >= KTOP) { T = tid * 16 + i; break; }
        }
        thr[bc] = T;
    }
}

// ---- kernel 3a: filter survivor list by threshold bin ----
__global__ void __launch_bounds__(256) k_collect2(
        const uint64_t* __restrict__ surv, const int* __restrict__ scnt,
        const int* __restrict__ ovf, const int* __restrict__ thr, int scap,
        uint64_t* __restrict__ cand, int* __restrict__ ccnt) {
    int bc = blockIdx.y;
    int n = scnt[bc];
    if (ovf[bc] || n > scap) return;   // fallback kernel handles this bc
    int T = thr[bc];
    const uint64_t* sv = surv + (size_t)bc * scap;
    for (int i = blockIdx.x * 256 + threadIdx.x; i < n; i += 256 * 8) {
        uint64_t k = sv[i];
        if ((int)(uint32_t)(k >> 51) >= T) {   // sigmoid-bits >> 19
            int pos = atomicAdd(&ccnt[bc], 1);
            if (pos < CAP) cand[(size_t)bc * CAP + pos] = k;
        }
    }
}

// ---- kernel 3b: fallback full rescan (early-exits unless survivor list overflowed) ----
__global__ void __launch_bounds__(256) k_collect_fb(
        const float* __restrict__ tl, const float* __restrict__ br,
        const float* __restrict__ ct, const int* __restrict__ thr,
        const int* __restrict__ scnt, const int* __restrict__ ovf, int scap,
        uint64_t* __restrict__ cand, int* __restrict__ ccnt) {
    int bc = blockIdx.y;
    if (!(ovf[bc] || scnt[bc] > scap)) return;
    int t = bc >> 3; int b = bc & 7;
    const float* heat = (t == 0) ? tl : (t == 1) ? br : ct;
    const float* hb = heat + (size_t)b * CHW;
    int T = thr[bc];
    const float NEG = -__builtin_inff();
    #pragma unroll
    for (int it = 0; it < 8; ++it) {
        int idx4 = blockIdx.x * 8192 + it * 1024 + threadIdx.x * 4;
        int rem = idx4 & (HW - 1);
        int y = rem >> 7, x = rem & (WW - 1);
        float4 m4 = *(const float4*)(hb + idx4);
        float4 u4 = make_float4(NEG, NEG, NEG, NEG);
        float4 d4 = make_float4(NEG, NEG, NEG, NEG);
        if (y > 0)      u4 = *(const float4*)(hb + idx4 - WW);
        if (y < HH - 1) d4 = *(const float4*)(hb + idx4 + WW);
        float c0 = fmaxf(fmaxf(u4.x, m4.x), d4.x);
        float c1 = fmaxf(fmaxf(u4.y, m4.y), d4.y);
        float c2 = fmaxf(fmaxf(u4.z, m4.z), d4.z);
        float c3 = fmaxf(fmaxf(u4.w, m4.w), d4.w);
        float cl = __shfl_up(c3, 1u);
        float cr = __shfl_down(c0, 1u);
        if (x == 0)      cl = NEG;
        if (x == WW - 4) cr = NEG;
        float w0 = fmaxf(fmaxf(cl, c0), c1);
        float w1 = fmaxf(fmaxf(c0, c1), c2);
        float w2 = fmaxf(fmaxf(c1, c2), c3);
        float w3 = fmaxf(fmaxf(c2, c3), cr);
        #define EMIT2(W, V, P) \
            if ((W) == (V)) { \
                uint32_t bt = __float_as_uint(sigmoidf(V)); \
                if ((int)(bt >> 19) >= T) { \
                    int pos = atomicAdd(&ccnt[bc], 1); \
                    if (pos < CAP) \
                        cand[(size_t)bc * CAP + pos] = \
                            ((uint64_t)bt << 32) | (uint32_t)(~(uint32_t)(idx4 + (P))); \
                } \
            }
        EMIT2(w0, m4.x, 0)
        EMIT2(w1, m4.y, 1)
        EMIT2(w2, m4.z, 2)
        EMIT2(w3, m4.w, 3)
        #undef EMIT2
    }
}

// descending bitonic sort of N u64 keys in LDS
template <int N>
__device__ void bitonic_desc(uint64_t* k) {
    for (int kk = 2; kk <= N; kk <<= 1) {
        for (int j = kk >> 1; j > 0; j >>= 1) {
            __syncthreads();
            for (int i = threadIdx.x; i < N; i += blockDim.x) {
                int l = i ^ j;
                if (l > i) {
                    uint64_t a = k[i], b = k[l];
                    bool up = ((i & kk) == 0);
                    if (up ? (a < b) : (a > b)) { k[i] = b; k[l] = a; }
                }
            }
        }
    }
    __syncthreads();
}

// ---- kernel 4: per (tensor,batch) sort candidates, emit top-100 corner data ----
__global__ void __launch_bounds__(1024) k_select(
        const uint64_t* __restrict__ cand, const int* __restrict__ ccnt,
        const float* __restrict__ tl_tag, const float* __restrict__ br_tag,
        const float* __restrict__ tl_regr, const float* __restrict__ br_regr,
        const float* __restrict__ ct_regr,
        float* __restrict__ cs, float* __restrict__ cx, float* __restrict__ cy,
        float* __restrict__ ce, int* __restrict__ ccls) {
    __shared__ uint64_t keys[CAP];
    int bc = blockIdx.x; int t = bc >> 3; int b = bc & 7;
    int n = ccnt[bc]; if (n > CAP) n = CAP;
    if (n <= 512) {   // typical: n in [100, ~500]
        for (int i = threadIdx.x; i < 512; i += 1024)
            keys[i] = (i < n) ? cand[(size_t)bc * CAP + i] : 0ull;
        bitonic_desc<512>(keys);
    } else {
        for (int i = threadIdx.x; i < CAP; i += 1024)
            keys[i] = (i < n) ? cand[(size_t)bc * CAP + i] : 0ull;
        bitonic_desc<CAP>(keys);
    }
    if (threadIdx.x < KTOP) {
        uint64_t key = keys[threadIdx.x];
        float s = __uint_as_float((uint32_t)(key >> 32));
        uint32_t idx = ~(uint32_t)key;
        int cls = (int)(idx >> 14);
        int rem = (int)(idx & (HW - 1));
        int y = rem >> 7, x = rem & (WW - 1);
        const float* regr = (t == 0) ? tl_regr : (t == 1) ? br_regr : ct_regr;
        float o0 = regr[((size_t)b * 2 + 0) * HW + rem];
        float o1 = regr[((size_t)b * 2 + 1) * HW + rem];
        float emb = 0.f;
        if (t == 0) emb = tl_tag[(size_t)b * HW + rem];
        else if (t == 1) emb = br_tag[(size_t)b * HW + rem];
        int o = bc * KTOP + threadIdx.x;
        cs[o] = s;
        cx[o] = (float)x + o0;
        cy[o] = (float)y + o1;
        ce[o] = emb;
        ccls[o] = cls;
    }
}

// ---- kernel 5: pairwise scoring, compact accepted pairs ----
__global__ void __launch_bounds__(1024) k_pairs(
        const float* __restrict__ cs, const float* __restrict__ cx,
        const float* __restrict__ cy, const float* __restrict__ ce,
        const int* __restrict__ ccls,
        uint64_t* __restrict__ acc, int* __restrict__ acnt) {
    int b = blockIdx.x;
    __shared__ float ts[KTOP], tx[KTOP], ty[KTOP], te[KTOP];
    __shared__ int   tc[KTOP];
    __shared__ float bs_[KTOP], bx[KTOP], by[KTOP], be[KTOP];
    __shared__ int   bcl[KTOP];
    int tid = threadIdx.x;
    if (tid < KTOP) {
        int o = (0 * NB + b) * KTOP + tid;
        ts[tid] = cs[o]; tx[tid] = cx[o]; ty[tid] = cy[o]; te[tid] = ce[o]; tc[tid] = ccls[o];
    } else if (tid >= 512 && tid < 512 + KTOP) {
        int k = tid - 512;
        int o = (1 * NB + b) * KTOP + k;
        bs_[k] = cs[o]; bx[k] = cx[o]; by[k] = cy[o]; be[k] = ce[o]; bcl[k] = ccls[o];
    }
    __syncthreads();
    for (int p = tid; p < NPAIR; p += 1024) {
        int i = p / KTOP, j = p - i * KTOP;
        bool rej = (tc[i] != bcl[j])
                 | (fabsf(te[i] - be[j]) > 0.5f)
                 | (bx[j] < tx[i])
                 | (by[j] < ty[i]);
        if (!rej) {
            float sc = (ts[i] + bs_[j]) * 0.5f;
            int pos = atomicAdd(&acnt[b], 1);
            if (pos < ACAP)
                acc[(size_t)b * ACAP + pos] =
                    ((uint64_t)__float_as_uint(sc) << 32) | (uint32_t)(~(uint32_t)p);
        }
    }
}

// ---- kernel 6: per-batch final top-1000 ----
__global__ void __launch_bounds__(1024) k_final(
        const uint64_t* __restrict__ acc, const int* __restrict__ acnt,
        const float* __restrict__ cs, const float* __restrict__ cx,
        const float* __restrict__ cy, const int* __restrict__ ccls,
        float* __restrict__ out) {
    int b = blockIdx.x;
    __shared__ uint64_t keys[ACAP];
    __shared__ int aidx[ACAP];
    int m = acnt[b]; if (m > ACAP) m = ACAP;
    if (m <= 256) {   // typical: m is tens
        for (int i = threadIdx.x; i < 256; i += 1024)
            keys[i] = (i < m) ? acc[(size_t)b * ACAP + i] : 0ull;
        bitonic_desc<256>(keys);
    } else {
        for (int i = threadIdx.x; i < ACAP; i += 1024)
            keys[i] = (i < m) ? acc[(size_t)b * ACAP + i] : 0ull;
        bitonic_desc<ACAP>(keys);
    }
    if ((int)threadIdx.x < m) aidx[threadIdx.x] = (int)(~(uint32_t)keys[threadIdx.x]);
    __syncthreads();
    for (int d = threadIdx.x; d < NDET; d += 1024) {
        int p; float sc;
        if (d < m) {
            p = aidx[d];
            sc = __uint_as_float((uint32_t)(keys[d] >> 32));
        } else {
            // (d-m)-th index NOT in accepted set, ascending (stable top_k over -1 ties)
            int r = d - m;
            int idx = r;
            for (;;) {
                int c = 0;
                for (int a = 0; a < m; ++a) c += (aidx[a] <= idx) ? 1 : 0;
                int ni = r + c;
                if (ni == idx) break;
                idx = ni;
            }
            p = idx; sc = -1.f;
        }
        int i = p / KTOP, j = p - i * KTOP;
        int ot = (0 * NB + b) * KTOP + i;
        int ob = (1 * NB + b) * KTOP + j;
        float* dr = out + ((size_t)b * NDET + d) * 8;
        dr[0] = cx[ot]; dr[1] = cy[ot]; dr[2] = cx[ob]; dr[3] = cy[ob];
        dr[4] = sc; dr[5] = cs[ot]; dr[6] = cs[ob]; dr[7] = (float)ccls[ot];
    }
    if (threadIdx.x < KTOP) {
        int oc = (2 * NB + b) * KTOP + threadIdx.x;
        float* cr = out + (size_t)NB * NDET * 8 + ((size_t)b * KTOP + threadIdx.x) * 4;
        cr[0] = cx[oc]; cr[1] = cy[oc]; cr[2] = (float)ccls[oc]; cr[3] = cs[oc];
    }
}

extern "C" void kernel_launch(void* const* d_in, const int* in_sizes, int n_in,
                              void* d_out, int out_size, void* d_ws, size_t ws_size,
                              hipStream_t stream) {
    const float* tl_heat = (const float*)d_in[0];
    const float* br_heat = (const float*)d_in[1];
    const float* ct_heat = (const float*)d_in[2];
    const float* tl_tag  = (const float*)d_in[3];
    const float* br_tag  = (const float*)d_in[4];
    const float* tl_regr = (const float*)d_in[5];
    const float* br_regr = (const float*)d_in[6];
    const float* ct_regr = (const float*)d_in[7];

    if (ws_size < (size_t)OFF_SURV) return;

    // survivor list capacity from remaining workspace (deterministic per run)
    size_t rem = (ws_size - OFF_SURV) / (24 * 8);
    int scap = (int)((rem > SCAP_MAX) ? SCAP_MAX : rem);

    char* ws = (char*)d_ws;
    uint64_t* cand = (uint64_t*)(ws + OFF_CAND);
    uint64_t* acc  = (uint64_t*)(ws + OFF_ACC);
    uint32_t* hist = (uint32_t*)(ws + OFF_HIST);
    int*   ccnt = (int*)(ws + OFF_CCNT);
    int*   acnt = (int*)(ws + OFF_ACNT);
    int*   scnt = (int*)(ws + OFF_SCNT);
    int*   ovf  = (int*)(ws + OFF_OVF);
    int*   thr  = (int*)(ws + OFF_THR);
    float* cs   = (float*)(ws + OFF_CS);
    float* cx   = (float*)(ws + OFF_CX);
    float* cy   = (float*)(ws + OFF_CY);
    float* ce   = (float*)(ws + OFF_CE);
    int*   ccls = (int*)(ws + OFF_CCLS);
    uint64_t* surv = (uint64_t*)(ws + OFF_SURV);

    hipMemsetAsync(ws + ZERO_OFF, 0, ZERO_BYTES, stream);

    dim3 gscan(CHW / 8192, 24);   // (160, 24)
    k_nms_hist<<<gscan, 256, 0, stream>>>(tl_heat, br_heat, ct_heat, hist,
                                          surv, scnt, ovf, scap);
    k_thresh<<<24, 256, 0, stream>>>(hist, thr);
    k_collect2<<<dim3(8, 24), 256, 0, stream>>>(surv, scnt, ovf, thr, scap, cand, ccnt);
    k_collect_fb<<<gscan, 256, 0, stream>>>(tl_heat, br_heat, ct_heat, thr,
                                            scnt, ovf, scap, cand, ccnt);
    k_select<<<24, 1024, 0, stream>>>(cand, ccnt, tl_tag, br_tag,
                                      tl_regr, br_regr, ct_regr,
                                      cs, cx, cy, ce, ccls);
    k_pairs<<<NB, 1024, 0, stream>>>(cs, cx, cy, ce, ccls, acc, acnt);
    k_final<<<NB, 1024, 0, stream>>>(acc, acnt, cs, cx, cy, ccls, (float*)d_out);
}